// Round 1
// baseline (1027.348 us; speedup 1.0000x reference)
//
#include <hip/hip_runtime.h>
#include <math.h>

#define Bsz 64
#define Nn  256
#define Hh  1024
#define NK  768   // N * K = 256*3

// ---------------------------------------------------------------------------
// Stage 1: weight[b*N + n][o] = dot(f[b,n,:], W_lin[o,:]) + b_lin[o]
// C[M=16384, 768] = A[16384,1024] @ W[768,1024]^T + bias
// Tiled 64x64x16, 256 threads, 4x4 microtile per thread.
// ---------------------------------------------------------------------------
__global__ __launch_bounds__(256) void gemm1_kernel(
    const float* __restrict__ A, const float* __restrict__ W,
    const float* __restrict__ bias, float* __restrict__ C)
{
    const int Kd = Hh;
    __shared__ float As[16][64 + 4];
    __shared__ float Ws[16][64 + 4];

    const int tid = threadIdx.x;
    const int tx = tid & 15;        // col group
    const int ty = tid >> 4;        // row group
    const int r  = tid >> 2;        // 0..63 load row
    const int c4 = tid & 3;         // 0..3 load col-quad

    const int row0 = blockIdx.y * 64;
    const int col0 = blockIdx.x * 64;

    const float* Ap = A + (size_t)(row0 + r) * Kd + c4 * 4;
    const float* Wp = W + (size_t)(col0 + r) * Kd + c4 * 4;

    float acc[4][4] = {};

    for (int k0 = 0; k0 < Kd; k0 += 16) {
        float4 av = *(const float4*)(Ap + k0);
        float4 wv = *(const float4*)(Wp + k0);
        __syncthreads();
        As[c4*4+0][r] = av.x; As[c4*4+1][r] = av.y;
        As[c4*4+2][r] = av.z; As[c4*4+3][r] = av.w;
        Ws[c4*4+0][r] = wv.x; Ws[c4*4+1][r] = wv.y;
        Ws[c4*4+2][r] = wv.z; Ws[c4*4+3][r] = wv.w;
        __syncthreads();
        #pragma unroll
        for (int kk = 0; kk < 16; ++kk) {
            float4 a = *(const float4*)&As[kk][ty * 4];
            float4 b = *(const float4*)&Ws[kk][tx * 4];
            float ar[4] = {a.x, a.y, a.z, a.w};
            float br[4] = {b.x, b.y, b.z, b.w};
            #pragma unroll
            for (int i = 0; i < 4; ++i)
                #pragma unroll
                for (int j = 0; j < 4; ++j)
                    acc[i][j] += ar[i] * br[j];
        }
    }

    const int colw = col0 + tx * 4;
    float4 bvec = *(const float4*)&bias[colw];
    float bb[4] = {bvec.x, bvec.y, bvec.z, bvec.w};
    #pragma unroll
    for (int i = 0; i < 4; ++i) {
        int row = row0 + ty * 4 + i;
        float4 o;
        o.x = acc[i][0] + bb[0];
        o.y = acc[i][1] + bb[1];
        o.z = acc[i][2] + bb[2];
        o.w = acc[i][3] + bb[3];
        *(float4*)&C[(size_t)row * NK + colw] = o;
    }
}

// ---------------------------------------------------------------------------
// Stage 2+3: out[b,o,h] = LN_h( sum_{i,t} k[b,i,h+t-1] * weight[b,o,i*3+t] )
// One block per (b, 16-o tile). 256 threads; thread owns h = tid*4..tid*4+3
// across all 16 o rows (64 accumulators). k rows double-buffered in LDS.
// ---------------------------------------------------------------------------
__global__ __launch_bounds__(256) void conv_ln_kernel(
    const float* __restrict__ Kin,   // [B,N,H]
    const float* __restrict__ Wg,    // [B*N, 768]
    const float* __restrict__ gamma, const float* __restrict__ beta,
    float* __restrict__ Out)
{
    const int b  = blockIdx.y;
    const int o0 = blockIdx.x * 16;
    const int tid = threadIdx.x;

    __shared__ float wbuf[16][NK];     // 48 KB: weight[b, o0..o0+15, :]
    __shared__ float krow[2][1032];    // [h]=k[h], [1024]=0 (right halo), [1030]=0 (left halo)
    __shared__ float red1[16][4], red2[16][4];

    // Load weight tile: 16 rows x 768 = 3072 float4 slots, 12 per thread.
    #pragma unroll
    for (int it = 0; it < 12; ++it) {
        int slot = tid + it * 256;
        int row = slot / 192;          // 768/4 = 192 float4 per row
        int c   = slot % 192;
        float4 v = *(const float4*)&Wg[(size_t)(b * Nn + o0 + row) * NK + c * 4];
        *(float4*)&wbuf[row][c * 4] = v;
    }
    if (tid < 2) {
        krow[tid][1024] = 0.0f;   // right halo (k[1024])
        krow[tid][1030] = 0.0f;   // left halo slot (k[-1])
    }

    float acc[16][4] = {};
    const int h0 = tid * 4;
    const float* kbase = Kin + (size_t)b * Nn * Hh;

    // prefetch i = 0
    {
        float4 v = *(const float4*)&kbase[h0];
        *(float4*)&krow[0][h0] = v;
    }

    for (int i = 0; i < Nn; ++i) {
        const int buf = i & 1;
        __syncthreads();
        if (i + 1 < Nn) {
            float4 v = *(const float4*)&kbase[(size_t)(i + 1) * Hh + h0];
            *(float4*)&krow[buf ^ 1][h0] = v;
        }
        float4 kv = *(const float4*)&krow[buf][h0];
        int   im1 = (h0 == 0) ? 1030 : (h0 - 1);
        float km1 = krow[buf][im1];
        float kp4 = krow[buf][h0 + 4];
        float kk[6] = {km1, kv.x, kv.y, kv.z, kv.w, kp4};
        const int wi = i * 3;
        #pragma unroll
        for (int oo = 0; oo < 16; ++oo) {
            float w0 = wbuf[oo][wi + 0];
            float w1 = wbuf[oo][wi + 1];
            float w2 = wbuf[oo][wi + 2];
            #pragma unroll
            for (int j = 0; j < 4; ++j)
                acc[oo][j] += w0 * kk[j] + w1 * kk[j + 1] + w2 * kk[j + 2];
        }
    }

    // LayerNorm reduction: per o row, sum and sumsq over 1024 h.
    const int lane = tid & 63;
    const int wid  = tid >> 6;
    #pragma unroll
    for (int oo = 0; oo < 16; ++oo) {
        float s1 = acc[oo][0] + acc[oo][1] + acc[oo][2] + acc[oo][3];
        float s2 = acc[oo][0]*acc[oo][0] + acc[oo][1]*acc[oo][1]
                 + acc[oo][2]*acc[oo][2] + acc[oo][3]*acc[oo][3];
        #pragma unroll
        for (int m = 1; m < 64; m <<= 1) {
            s1 += __shfl_xor(s1, m, 64);
            s2 += __shfl_xor(s2, m, 64);
        }
        if (lane == 0) { red1[oo][wid] = s1; red2[oo][wid] = s2; }
    }
    __syncthreads();

    float4 gv = *(const float4*)&gamma[h0];
    float4 bv = *(const float4*)&beta[h0];
    float g[4]  = {gv.x, gv.y, gv.z, gv.w};
    float be[4] = {bv.x, bv.y, bv.z, bv.w};

    #pragma unroll
    for (int oo = 0; oo < 16; ++oo) {
        float S1 = red1[oo][0] + red1[oo][1] + red1[oo][2] + red1[oo][3];
        float S2 = red2[oo][0] + red2[oo][1] + red2[oo][2] + red2[oo][3];
        float mu   = S1 * (1.0f / 1024.0f);
        float var  = S2 * (1.0f / 1024.0f) - mu * mu;
        float rstd = rsqrtf(var + 1e-5f);
        float4 o;
        o.x = (acc[oo][0] - mu) * rstd * g[0] + be[0];
        o.y = (acc[oo][1] - mu) * rstd * g[1] + be[1];
        o.z = (acc[oo][2] - mu) * rstd * g[2] + be[2];
        o.w = (acc[oo][3] - mu) * rstd * g[3] + be[3];
        *(float4*)&Out[(size_t)(b * Nn + o0 + oo) * Hh + h0] = o;
    }
}

extern "C" void kernel_launch(void* const* d_in, const int* in_sizes, int n_in,
                              void* d_out, int out_size, void* d_ws, size_t ws_size,
                              hipStream_t stream) {
    const float* f      = (const float*)d_in[0];
    const float* kin    = (const float*)d_in[1];
    const float* W_lin  = (const float*)d_in[2];
    const float* b_lin  = (const float*)d_in[3];
    const float* gamma  = (const float*)d_in[4];
    const float* beta   = (const float*)d_in[5];
    float* out = (float*)d_out;
    float* wgt = (float*)d_ws;   // [B*N, 768] fp32 = 50.3 MB

    dim3 g1(NK / 64, (Bsz * Nn) / 64);   // (12, 256)
    gemm1_kernel<<<g1, 256, 0, stream>>>(f, W_lin, b_lin, wgt);

    dim3 g2(Nn / 16, Bsz);               // (16, 64)
    conv_ln_kernel<<<g2, 256, 0, stream>>>(kin, wgt, gamma, beta, out);
}

// Round 2
// 317.538 us; speedup vs baseline: 3.2354x; 3.2354x over previous
//
#include <hip/hip_runtime.h>
#include <math.h>

#define Bsz 64
#define Nn  256
#define Hh  1024
#define NK  768

typedef __bf16 bf16;
typedef bf16 bf16x4 __attribute__((ext_vector_type(4)));
typedef bf16 bf16x8 __attribute__((ext_vector_type(8)));
typedef float floatx4 __attribute__((ext_vector_type(4)));

__device__ __forceinline__ void gl_lds16(const bf16* g, bf16* l) {
    __builtin_amdgcn_global_load_lds(
        (__attribute__((address_space(1))) void*)(g),
        (__attribute__((address_space(3))) void*)(l), 16, 0, 0);
}

// ---------------------------------------------------------------------------
// fp32 -> bf16 cast (vectorized)
// ---------------------------------------------------------------------------
__global__ __launch_bounds__(256) void cast_bf16_kernel(
    const float* __restrict__ src, bf16* __restrict__ dst, int n4)
{
    int i = blockIdx.x * 256 + threadIdx.x;
    if (i < n4) {
        float4 v = ((const float4*)src)[i];
        bf16x4 o = { (bf16)v.x, (bf16)v.y, (bf16)v.z, (bf16)v.w };
        ((bf16x4*)dst)[i] = o;
    }
}

// ---------------------------------------------------------------------------
// Stage 1: C[row=(b,n)][col=o'] = f_bf[row,:] . W_lin[o',:]  (K=1024)
// 128x128 tile, 4 waves of 64x64, mfma_f32_16x16x32_bf16.
// Epilogue: +bias, scatter bf16 to wgt3[b][t=o'%3][n][i=o'/3].
// ---------------------------------------------------------------------------
__global__ __launch_bounds__(256) void gemm1_mfma(
    const bf16* __restrict__ A,    // [16384][1024]
    const bf16* __restrict__ Bw,   // [768][1024]
    const float* __restrict__ bias,
    bf16* __restrict__ wgt3)       // [64*3][256][256]
{
    __shared__ bf16 As[128 * 32];
    __shared__ bf16 Bs[128 * 32];
    const int tid  = threadIdx.x;
    const int wave = tid >> 6, lane = tid & 63;
    const int row0 = blockIdx.y * 128;
    const int col0 = blockIdx.x * 128;

    const int s0 = (wave * 2 + 0) * 64 + lane;
    const int s1 = (wave * 2 + 1) * 64 + lane;
    const bf16* gA0 = A  + (size_t)(row0 + (s0 >> 2)) * Hh + (s0 & 3) * 8;
    const bf16* gA1 = A  + (size_t)(row0 + (s1 >> 2)) * Hh + (s1 & 3) * 8;
    const bf16* gB0 = Bw + (size_t)(col0 + (s0 >> 2)) * Hh + (s0 & 3) * 8;
    const bf16* gB1 = Bw + (size_t)(col0 + (s1 >> 2)) * Hh + (s1 & 3) * 8;
    bf16* lA0 = &As[(wave * 2 + 0) * 512];
    bf16* lA1 = &As[(wave * 2 + 1) * 512];
    bf16* lB0 = &Bs[(wave * 2 + 0) * 512];
    bf16* lB1 = &Bs[(wave * 2 + 1) * 512];

    const int wm = wave & 1, wn = wave >> 1;
    const int fm = lane & 15, koct = (lane >> 4) * 8;

    floatx4 zero = {0.f, 0.f, 0.f, 0.f};
    floatx4 acc[4][4];
    #pragma unroll
    for (int i = 0; i < 4; ++i)
        #pragma unroll
        for (int j = 0; j < 4; ++j) acc[i][j] = zero;

    for (int k0 = 0; k0 < Hh; k0 += 32) {
        gl_lds16(gA0 + k0, lA0);
        gl_lds16(gA1 + k0, lA1);
        gl_lds16(gB0 + k0, lB0);
        gl_lds16(gB1 + k0, lB1);
        __syncthreads();
        bf16x8 af[4], bfr[4];
        #pragma unroll
        for (int mt = 0; mt < 4; ++mt)
            af[mt] = *(const bf16x8*)&As[(wm * 64 + mt * 16 + fm) * 32 + koct];
        #pragma unroll
        for (int nt = 0; nt < 4; ++nt)
            bfr[nt] = *(const bf16x8*)&Bs[(wn * 64 + nt * 16 + fm) * 32 + koct];
        #pragma unroll
        for (int mt = 0; mt < 4; ++mt)
            #pragma unroll
            for (int nt = 0; nt < 4; ++nt)
                acc[mt][nt] = __builtin_amdgcn_mfma_f32_16x16x32_bf16(
                    af[mt], bfr[nt], acc[mt][nt], 0, 0, 0);
        __syncthreads();
    }

    const int b = row0 >> 8;
    #pragma unroll
    for (int nt = 0; nt < 4; ++nt) {
        int col = col0 + wn * 64 + nt * 16 + fm;      // o'
        float bl = bias[col];
        int ii = col / 3;
        int tt = col - ii * 3;
        bf16* dst = wgt3 + ((size_t)(b * 3 + tt) << 16) + ii;
        #pragma unroll
        for (int mt = 0; mt < 4; ++mt) {
            int nr = (row0 & 255) + wm * 64 + mt * 16 + (lane >> 4) * 4;
            #pragma unroll
            for (int r = 0; r < 4; ++r)
                dst[(size_t)(nr + r) << 8] = (bf16)(acc[mt][nt][r] + bl);
        }
    }
}

// ---------------------------------------------------------------------------
// Stage 2: conv[b][o][h] = sum_{t,i} wgt3[b][t][o][i] * k[b][i][h+t-1]
// Block = (b, 128-o tile, 128-h tile). K-loop: 8 i-chunks of 32, 3 taps each.
// k-tile transpose-staged once per chunk into Ks[h+halo][i], reused 3x.
// ---------------------------------------------------------------------------
__global__ __launch_bounds__(256) void conv_mfma(
    const bf16* __restrict__ kbf,   // [64][256][1024]
    const bf16* __restrict__ wgt3,  // [64*3][256][256]
    bf16* __restrict__ conv)        // [64][256][1024]
{
    __shared__ bf16 As[3 * 128 * 32];   // [t][o][i]   24 KB
    __shared__ bf16 Ks[130 * 40];       // [hh][i] pitch 40, 10.4 KB
    const int tid  = threadIdx.x;
    const int wave = tid >> 6, lane = tid & 63;
    const int b  = blockIdx.z;
    const int o0 = blockIdx.y * 128;
    const int h0 = blockIdx.x * 128;
    const int wm = wave & 1, wn = wave >> 1;
    const int fm = lane & 15, koct = (lane >> 4) * 8;

    const bf16* gA[6];
    bf16* lA[6];
    #pragma unroll
    for (int j = 0; j < 6; ++j) {
        int s = (wave * 6 + j) * 64 + lane;
        int t = s >> 9, rem = s & 511;
        int o = rem >> 2, iq = rem & 3;
        gA[j] = wgt3 + ((size_t)(b * 3 + t) << 16) + ((size_t)(o0 + o) << 8) + iq * 8;
        lA[j] = &As[(wave * 6 + j) * 512];
    }
    const int ki  = tid & 31;
    const int kho = tid >> 5;                   // 0..7
    const bf16* kbase = kbf + ((size_t)b << 18);

    floatx4 zero = {0.f, 0.f, 0.f, 0.f};
    floatx4 acc[4][4];
    #pragma unroll
    for (int i = 0; i < 4; ++i)
        #pragma unroll
        for (int j = 0; j < 4; ++j) acc[i][j] = zero;

    for (int ic = 0; ic < 8; ++ic) {
        const int i0 = ic * 32;
        __syncthreads();
        #pragma unroll
        for (int j = 0; j < 6; ++j) gl_lds16(gA[j] + i0, lA[j]);
        #pragma unroll
        for (int p = 0; p < 2; ++p) {
            int ho = kho + p * 8;               // 0..15
            bf16x8 v = *(const bf16x8*)&kbase[(size_t)(i0 + ki) * Hh + h0 + ho * 8];
            #pragma unroll
            for (int j = 0; j < 8; ++j)
                Ks[(1 + ho * 8 + j) * 40 + ki] = v[j];
        }
        if (tid < 32) {
            Ks[tid] = (h0 > 0) ? kbase[(size_t)(i0 + tid) * Hh + h0 - 1] : (bf16)0.f;
        } else if (tid < 64) {
            int i2 = tid - 32;
            Ks[129 * 40 + i2] = (h0 + 128 < Hh)
                ? kbase[(size_t)(i0 + i2) * Hh + h0 + 128] : (bf16)0.f;
        }
        __syncthreads();
        #pragma unroll
        for (int t = 0; t < 3; ++t) {
            bf16x8 af[4], bfr[4];
            #pragma unroll
            for (int mt = 0; mt < 4; ++mt)
                af[mt] = *(const bf16x8*)&As[t * 4096 + (wm * 64 + mt * 16 + fm) * 32 + koct];
            #pragma unroll
            for (int nt = 0; nt < 4; ++nt)
                bfr[nt] = *(const bf16x8*)&Ks[(wn * 64 + nt * 16 + fm + t) * 40 + koct];
            #pragma unroll
            for (int mt = 0; mt < 4; ++mt)
                #pragma unroll
                for (int nt = 0; nt < 4; ++nt)
                    acc[mt][nt] = __builtin_amdgcn_mfma_f32_16x16x32_bf16(
                        af[mt], bfr[nt], acc[mt][nt], 0, 0, 0);
        }
    }

    #pragma unroll
    for (int mt = 0; mt < 4; ++mt) {
        int o = o0 + wm * 64 + mt * 16 + (lane >> 4) * 4;
        #pragma unroll
        for (int nt = 0; nt < 4; ++nt) {
            int h = h0 + wn * 64 + nt * 16 + fm;
            #pragma unroll
            for (int r = 0; r < 4; ++r)
                conv[((size_t)(b * 256 + o + r) << 10) + h] = (bf16)acc[mt][nt][r];
        }
    }
}

// ---------------------------------------------------------------------------
// Stage 3: LayerNorm over H per (b,o) row. One block per row.
// ---------------------------------------------------------------------------
__global__ __launch_bounds__(256) void ln_kernel(
    const bf16* __restrict__ conv, const float* __restrict__ gamma,
    const float* __restrict__ beta, float* __restrict__ out)
{
    const int row = blockIdx.x;
    const int tid = threadIdx.x;
    bf16x4 v = ((const bf16x4*)(conv + ((size_t)row << 10)))[tid];
    float x[4] = {(float)v[0], (float)v[1], (float)v[2], (float)v[3]};
    float s1 = x[0] + x[1] + x[2] + x[3];
    float s2 = x[0]*x[0] + x[1]*x[1] + x[2]*x[2] + x[3]*x[3];
    #pragma unroll
    for (int m = 1; m < 64; m <<= 1) {
        s1 += __shfl_xor(s1, m, 64);
        s2 += __shfl_xor(s2, m, 64);
    }
    __shared__ float r1[4], r2[4];
    if ((tid & 63) == 0) { r1[tid >> 6] = s1; r2[tid >> 6] = s2; }
    __syncthreads();
    float S1 = r1[0] + r1[1] + r1[2] + r1[3];
    float S2 = r2[0] + r2[1] + r2[2] + r2[3];
    float mu   = S1 * (1.0f / 1024.0f);
    float var  = S2 * (1.0f / 1024.0f) - mu * mu;
    float rstd = rsqrtf(var + 1e-5f);
    float4 g  = ((const float4*)gamma)[tid];
    float4 be = ((const float4*)beta)[tid];
    float4 o;
    o.x = (x[0] - mu) * rstd * g.x + be.x;
    o.y = (x[1] - mu) * rstd * g.y + be.y;
    o.z = (x[2] - mu) * rstd * g.z + be.z;
    o.w = (x[3] - mu) * rstd * g.w + be.w;
    ((float4*)(out + ((size_t)row << 10)))[tid] = o;
}

extern "C" void kernel_launch(void* const* d_in, const int* in_sizes, int n_in,
                              void* d_out, int out_size, void* d_ws, size_t ws_size,
                              hipStream_t stream) {
    const float* f     = (const float*)d_in[0];
    const float* kin   = (const float*)d_in[1];
    const float* W_lin = (const float*)d_in[2];
    const float* b_lin = (const float*)d_in[3];
    const float* gamma = (const float*)d_in[4];
    const float* beta  = (const float*)d_in[5];
    float* out = (float*)d_out;

    char* ws = (char*)d_ws;
    bf16* fbf  = (bf16*)(ws);                   // 33.55 MB  (conv aliases after stage 1)
    bf16* kbf  = (bf16*)(ws + 33554432);        // 33.55 MB
    bf16* wlbf = (bf16*)(ws + 67108864);        // 1.57 MB
    bf16* wgt3 = (bf16*)(ws + 68681728);        // 25.17 MB  -> total ~93.8 MB
    bf16* conv = fbf;

    cast_bf16_kernel<<<16384, 256, 0, stream>>>(f,   fbf,  4194304);
    cast_bf16_kernel<<<16384, 256, 0, stream>>>(kin, kbf,  4194304);
    cast_bf16_kernel<<<768,   256, 0, stream>>>(W_lin, wlbf, 196608);

    gemm1_mfma<<<dim3(6, 128), 256, 0, stream>>>(fbf, wlbf, b_lin, wgt3);
    conv_mfma<<<dim3(8, 2, 64), 256, 0, stream>>>(kbf, wgt3, conv);
    ln_kernel<<<16384, 256, 0, stream>>>(conv, gamma, beta, out);
}

// Round 3
// 287.289 us; speedup vs baseline: 3.5760x; 1.1053x over previous
//
#include <hip/hip_runtime.h>
#include <math.h>

#define Bsz 64
#define Nn  256
#define Hh  1024
#define NK  768

typedef __bf16 bf16;
typedef bf16 bf16x4 __attribute__((ext_vector_type(4)));
typedef bf16 bf16x8 __attribute__((ext_vector_type(8)));
typedef float floatx4 __attribute__((ext_vector_type(4)));

__device__ __forceinline__ void gl_lds16(const bf16* g, bf16* l) {
    __builtin_amdgcn_global_load_lds(
        (__attribute__((address_space(1))) void*)(g),
        (__attribute__((address_space(3))) void*)(l), 16, 0, 0);
}

// ---------------------------------------------------------------------------
// Fused cast: f -> bf16 (4194304 float4), W_lin -> bf16 (196608 float4)
// ---------------------------------------------------------------------------
__global__ __launch_bounds__(256) void cast2_kernel(
    const float* __restrict__ f, const float* __restrict__ wl,
    bf16* __restrict__ fbf, bf16* __restrict__ wlbf)
{
    int i = blockIdx.x * 256 + threadIdx.x;
    if (i < 4194304) {
        float4 v = ((const float4*)f)[i];
        bf16x4 o = { (bf16)v.x, (bf16)v.y, (bf16)v.z, (bf16)v.w };
        ((bf16x4*)fbf)[i] = o;
    } else {
        int j = i - 4194304;
        if (j < 196608) {
            float4 v = ((const float4*)wl)[j];
            bf16x4 o = { (bf16)v.x, (bf16)v.y, (bf16)v.z, (bf16)v.w };
            ((bf16x4*)wlbf)[j] = o;
        }
    }
}

// ---------------------------------------------------------------------------
// Stage 1: C[row=(b,n)][col=o'] = f_bf[row,:] . W_lin[o',:]  (K=1024)
// 128x128 tile, BK=64 (two BK=32 LDS stages per barrier pair), 4 waves.
// Epilogue: +bias, scatter bf16 to wgt3[b][t=o'%3][n][i=o'/3].
// ---------------------------------------------------------------------------
__global__ __launch_bounds__(256) void gemm1_mfma(
    const bf16* __restrict__ A,    // [16384][1024]
    const bf16* __restrict__ Bw,   // [768][1024]
    const float* __restrict__ bias,
    bf16* __restrict__ wgt3)       // [64*3][256][256]
{
    __shared__ bf16 As[2][128 * 32];
    __shared__ bf16 Bs[2][128 * 32];
    const int tid  = threadIdx.x;
    const int wave = tid >> 6, lane = tid & 63;
    const int row0 = blockIdx.y * 128;
    const int col0 = blockIdx.x * 128;

    const bf16* gA[4]; const bf16* gB[4];
    bf16* lA[4]; bf16* lB[4];
    #pragma unroll
    for (int j = 0; j < 4; ++j) {
        int sg  = wave * 4 + j;        // 0..15
        int reg = sg >> 3;             // k-half (0..1)
        int wi  = sg & 7;
        int row = wi * 16 + (lane >> 2);
        int quad = lane & 3;
        gA[j] = A  + (size_t)(row0 + row) * Hh + reg * 32 + quad * 8;
        gB[j] = Bw + (size_t)(col0 + row) * Hh + reg * 32 + quad * 8;
        lA[j] = &As[reg][wi * 512];
        lB[j] = &Bs[reg][wi * 512];
    }

    const int wm = wave & 1, wn = wave >> 1;
    const int fm = lane & 15, koct = (lane >> 4) * 8;

    floatx4 zero = {0.f, 0.f, 0.f, 0.f};
    floatx4 acc[4][4];
    #pragma unroll
    for (int i = 0; i < 4; ++i)
        #pragma unroll
        for (int j = 0; j < 4; ++j) acc[i][j] = zero;

    for (int k0 = 0; k0 < Hh; k0 += 64) {
        #pragma unroll
        for (int j = 0; j < 4; ++j) {
            gl_lds16(gA[j] + k0, lA[j]);
            gl_lds16(gB[j] + k0, lB[j]);
        }
        __syncthreads();
        #pragma unroll
        for (int q = 0; q < 2; ++q) {
            bf16x8 af[4], bfr[4];
            #pragma unroll
            for (int mt = 0; mt < 4; ++mt)
                af[mt] = *(const bf16x8*)&As[q][(wm * 64 + mt * 16 + fm) * 32 + koct];
            #pragma unroll
            for (int nt = 0; nt < 4; ++nt)
                bfr[nt] = *(const bf16x8*)&Bs[q][(wn * 64 + nt * 16 + fm) * 32 + koct];
            #pragma unroll
            for (int mt = 0; mt < 4; ++mt)
                #pragma unroll
                for (int nt = 0; nt < 4; ++nt)
                    acc[mt][nt] = __builtin_amdgcn_mfma_f32_16x16x32_bf16(
                        af[mt], bfr[nt], acc[mt][nt], 0, 0, 0);
        }
        __syncthreads();
    }

    const int b = row0 >> 8;
    #pragma unroll
    for (int nt = 0; nt < 4; ++nt) {
        int col = col0 + wn * 64 + nt * 16 + fm;      // o'
        float bl = bias[col];
        int ii = col / 3;
        int tt = col - ii * 3;
        bf16* dst = wgt3 + ((size_t)(b * 3 + tt) << 16) + ii;
        #pragma unroll
        for (int mt = 0; mt < 4; ++mt) {
            int nr = (row0 & 255) + wm * 64 + mt * 16 + (lane >> 4) * 4;
            #pragma unroll
            for (int r = 0; r < 4; ++r)
                dst[(size_t)(nr + r) << 8] = (bf16)(acc[mt][nt][r] + bl);
        }
    }
}

// ---------------------------------------------------------------------------
// Stage 2: out[b][o][h] = sum_{t,i} wgt3[b][t][o][i] * k[b][i][h+t-1]
// Block = (b, 128-o tile, 256-h tile). 8 i-chunks of 32, 3 taps each.
// k read as fp32 (cast fused into transpose staging). fp32 output to d_out.
// ---------------------------------------------------------------------------
__global__ __launch_bounds__(256, 2) void conv_mfma(
    const float* __restrict__ kin,  // [64][256][1024] fp32
    const bf16* __restrict__ wgt3,  // [64*3][256][256]
    float* __restrict__ out)        // [64][256][1024] fp32
{
    __shared__ bf16 As[3 * 128 * 32];   // [t][o][i]   24 KB
    __shared__ bf16 Ks[258 * 40];       // [hh][i] pitch 40, 20.6 KB
    const int tid  = threadIdx.x;
    const int wave = tid >> 6, lane = tid & 63;
    const int b  = blockIdx.z;
    const int o0 = blockIdx.y * 128;
    const int h0 = blockIdx.x * 256;
    const int wm = wave & 1, wn = wave >> 1;   // wn: h-half (0..1)
    const int fm = lane & 15, koct = (lane >> 4) * 8;

    const bf16* gA[6];
    bf16* lA[6];
    #pragma unroll
    for (int j = 0; j < 6; ++j) {
        int s = (wave * 6 + j) * 64 + lane;
        int t = s >> 9, rem = s & 511;
        int o = rem >> 2, iq = rem & 3;
        gA[j] = wgt3 + ((size_t)(b * 3 + t) << 16) + ((size_t)(o0 + o) << 8) + iq * 8;
        lA[j] = &As[(wave * 6 + j) * 512];
    }
    const int ki  = tid & 31;
    const int kho = tid >> 5;                   // 0..7
    const float* kb = kin + (size_t)b * Nn * Hh;

    floatx4 zero = {0.f, 0.f, 0.f, 0.f};
    floatx4 acc[4][8];
    #pragma unroll
    for (int i = 0; i < 4; ++i)
        #pragma unroll
        for (int j = 0; j < 8; ++j) acc[i][j] = zero;

    for (int ic = 0; ic < 8; ++ic) {
        const int i0 = ic * 32;
        __syncthreads();
        #pragma unroll
        for (int j = 0; j < 6; ++j) gl_lds16(gA[j] + i0, lA[j]);
        #pragma unroll
        for (int p = 0; p < 4; ++p) {
            int ho = kho + p * 8;               // 0..31
            const float* src = kb + (size_t)(i0 + ki) * Hh + h0 + ho * 8;
            float4 v0 = ((const float4*)src)[0];
            float4 v1 = ((const float4*)src)[1];
            int rb = (1 + ho * 8) * 40 + ki;
            Ks[rb + 0 * 40] = (bf16)v0.x; Ks[rb + 1 * 40] = (bf16)v0.y;
            Ks[rb + 2 * 40] = (bf16)v0.z; Ks[rb + 3 * 40] = (bf16)v0.w;
            Ks[rb + 4 * 40] = (bf16)v1.x; Ks[rb + 5 * 40] = (bf16)v1.y;
            Ks[rb + 6 * 40] = (bf16)v1.z; Ks[rb + 7 * 40] = (bf16)v1.w;
        }
        if (tid < 32) {
            Ks[tid] = (h0 > 0) ? (bf16)kb[(size_t)(i0 + tid) * Hh + h0 - 1] : (bf16)0.f;
        } else if (tid < 64) {
            int i2 = tid - 32;
            Ks[257 * 40 + i2] = (h0 + 256 < Hh)
                ? (bf16)kb[(size_t)(i0 + i2) * Hh + h0 + 256] : (bf16)0.f;
        }
        __syncthreads();
        #pragma unroll
        for (int t = 0; t < 3; ++t) {
            bf16x8 af[4], bfr[8];
            #pragma unroll
            for (int mt = 0; mt < 4; ++mt)
                af[mt] = *(const bf16x8*)&As[t * 4096 + (wm * 64 + mt * 16 + fm) * 32 + koct];
            #pragma unroll
            for (int nt = 0; nt < 8; ++nt)
                bfr[nt] = *(const bf16x8*)&Ks[(wn * 128 + nt * 16 + fm + t) * 40 + koct];
            #pragma unroll
            for (int mt = 0; mt < 4; ++mt)
                #pragma unroll
                for (int nt = 0; nt < 8; ++nt)
                    acc[mt][nt] = __builtin_amdgcn_mfma_f32_16x16x32_bf16(
                        af[mt], bfr[nt], acc[mt][nt], 0, 0, 0);
        }
    }

    #pragma unroll
    for (int mt = 0; mt < 4; ++mt) {
        int o = o0 + wm * 64 + mt * 16 + (lane >> 4) * 4;
        #pragma unroll
        for (int nt = 0; nt < 8; ++nt) {
            int h = h0 + wn * 128 + nt * 16 + fm;
            #pragma unroll
            for (int r = 0; r < 4; ++r)
                out[((size_t)(b * 256 + o + r) << 10) + h] = acc[mt][nt][r];
        }
    }
}

// ---------------------------------------------------------------------------
// Stage 3: LayerNorm over H per (b,o) row, in place on d_out (fp32).
// ---------------------------------------------------------------------------
__global__ __launch_bounds__(256) void ln_kernel(
    float* __restrict__ io, const float* __restrict__ gamma,
    const float* __restrict__ beta)
{
    const int row = blockIdx.x;
    const int tid = threadIdx.x;
    float* p = io + ((size_t)row << 10);
    float4 v = ((const float4*)p)[tid];
    float x[4] = {v.x, v.y, v.z, v.w};
    float s1 = x[0] + x[1] + x[2] + x[3];
    float s2 = x[0]*x[0] + x[1]*x[1] + x[2]*x[2] + x[3]*x[3];
    #pragma unroll
    for (int m = 1; m < 64; m <<= 1) {
        s1 += __shfl_xor(s1, m, 64);
        s2 += __shfl_xor(s2, m, 64);
    }
    __shared__ float r1[4], r2[4];
    if ((tid & 63) == 0) { r1[tid >> 6] = s1; r2[tid >> 6] = s2; }
    __syncthreads();
    float S1 = r1[0] + r1[1] + r1[2] + r1[3];
    float S2 = r2[0] + r2[1] + r2[2] + r2[3];
    float mu   = S1 * (1.0f / 1024.0f);
    float var  = S2 * (1.0f / 1024.0f) - mu * mu;
    float rstd = rsqrtf(var + 1e-5f);
    float4 g  = ((const float4*)gamma)[tid];
    float4 be = ((const float4*)beta)[tid];
    float4 o;
    o.x = (x[0] - mu) * rstd * g.x + be.x;
    o.y = (x[1] - mu) * rstd * g.y + be.y;
    o.z = (x[2] - mu) * rstd * g.z + be.z;
    o.w = (x[3] - mu) * rstd * g.w + be.w;
    ((float4*)p)[tid] = o;
}

extern "C" void kernel_launch(void* const* d_in, const int* in_sizes, int n_in,
                              void* d_out, int out_size, void* d_ws, size_t ws_size,
                              hipStream_t stream) {
    const float* f     = (const float*)d_in[0];
    const float* kin   = (const float*)d_in[1];
    const float* W_lin = (const float*)d_in[2];
    const float* b_lin = (const float*)d_in[3];
    const float* gamma = (const float*)d_in[4];
    const float* beta  = (const float*)d_in[5];
    float* out = (float*)d_out;

    char* ws = (char*)d_ws;
    bf16* fbf  = (bf16*)(ws);                   // 33.55 MB
    bf16* wlbf = (bf16*)(ws + 33554432);        // 1.57 MB
    bf16* wgt3 = (bf16*)(ws + 35127296);        // 25.17 MB -> total ~60 MB

    cast2_kernel<<<17152, 256, 0, stream>>>(f, W_lin, fbf, wlbf);
    gemm1_mfma<<<dim3(6, 128), 256, 0, stream>>>(fbf, wlbf, b_lin, wgt3);
    conv_mfma<<<dim3(4, 2, 64), 256, 0, stream>>>(kin, wgt3, out);
    ln_kernel<<<16384, 256, 0, stream>>>(out, gamma, beta);
}

// Round 5
// 287.006 us; speedup vs baseline: 3.5795x; 1.0010x over previous
//
#include <hip/hip_runtime.h>
#include <math.h>

#define Bsz 64
#define Nn  256
#define Hh  1024
#define NK  768

typedef __bf16 bf16;
typedef bf16 bf16x4 __attribute__((ext_vector_type(4)));
typedef bf16 bf16x8 __attribute__((ext_vector_type(8)));
typedef float floatx4 __attribute__((ext_vector_type(4)));

#define KT_ROWS   1026          // kTp rows per batch: h = -1 .. 1024
#define KT_BSTRIDE (KT_ROWS * 256)   // 262656 elements per batch

__device__ __forceinline__ void gl_lds16(const bf16* g, bf16* l) {
    __builtin_amdgcn_global_load_lds(
        (__attribute__((address_space(1))) void*)(g),
        (__attribute__((address_space(3))) void*)(l), 16, 0, 0);
}

// ---------------------------------------------------------------------------
// Fused cast: f -> bf16 (4194304 float4), W_lin -> bf16 (196608 float4)
// ---------------------------------------------------------------------------
__global__ __launch_bounds__(256) void cast2_kernel(
    const float* __restrict__ f, const float* __restrict__ wl,
    bf16* __restrict__ fbf, bf16* __restrict__ wlbf)
{
    int i = blockIdx.x * 256 + threadIdx.x;
    if (i < 4194304) {
        float4 v = ((const float4*)f)[i];
        bf16x4 o = { (bf16)v.x, (bf16)v.y, (bf16)v.z, (bf16)v.w };
        ((bf16x4*)fbf)[i] = o;
    } else {
        int j = i - 4194304;
        if (j < 196608) {
            float4 v = ((const float4*)wl)[j];
            bf16x4 o = { (bf16)v.x, (bf16)v.y, (bf16)v.z, (bf16)v.w };
            ((bf16x4*)wlbf)[j] = o;
        }
    }
}

// ---------------------------------------------------------------------------
// k transpose: kin[b][i][h] fp32 -> kTp[b][h+1][i] bf16, halo rows zeroed.
// Block = (b, 64-i tile, 64-h tile). LDS tile 64x64 bf16, pitch 72.
// Write-back: 2 passes x 8 bf16 per thread (4096 elements total).
// ---------------------------------------------------------------------------
__global__ __launch_bounds__(256) void kT_kernel(
    const float* __restrict__ kin, bf16* __restrict__ kTp)
{
    __shared__ bf16 T[64 * 72];
    const int tid = threadIdx.x;
    const int b = blockIdx.z, i0 = blockIdx.y * 64, h0 = blockIdx.x * 64;
    const float* src = kin + ((size_t)b << 18);
    bf16* dstb = kTp + (size_t)b * KT_BSTRIDE;

    if (blockIdx.x == 0 && blockIdx.y == 0) {
        dstb[tid] = (bf16)0.f;                       // h = -1 row
        dstb[(size_t)1025 * 256 + tid] = (bf16)0.f;  // h = 1024 row
    }
    #pragma unroll
    for (int j = 0; j < 4; ++j) {
        int s = tid + j * 256;
        int il = s >> 4, c4 = s & 15;
        float4 v = *(const float4*)&src[(size_t)(i0 + il) * Hh + h0 + c4 * 4];
        T[(c4 * 4 + 0) * 72 + il] = (bf16)v.x;
        T[(c4 * 4 + 1) * 72 + il] = (bf16)v.y;
        T[(c4 * 4 + 2) * 72 + il] = (bf16)v.z;
        T[(c4 * 4 + 3) * 72 + il] = (bf16)v.w;
    }
    __syncthreads();
    #pragma unroll
    for (int p = 0; p < 2; ++p) {
        int hl = (tid >> 3) + p * 32;    // 0..63
        int q  = tid & 7;                // 0..7 -> i_local 0..63
        bf16x8 v = *(const bf16x8*)&T[hl * 72 + q * 8];
        *(bf16x8*)&dstb[(size_t)(h0 + hl + 1) * 256 + i0 + q * 8] = v;
    }
}

// ---------------------------------------------------------------------------
// Stage 1: C[row=(b,n)][col=o'] = f_bf[row,:] . W_lin[o',:]  (K=1024)
// 128x96 tile (96 = 3 taps x 32 i), BK=64, 4 waves (2m x 2n of 64x48).
// Epilogue via LDS: +bias, unscramble to wgt3[b][t][n][i], coalesced 16B.
// ---------------------------------------------------------------------------
__global__ __launch_bounds__(256) void gemm1_mfma(
    const bf16* __restrict__ A,    // [16384][1024]
    const bf16* __restrict__ Bw,   // [768][1024]
    const float* __restrict__ bias,
    bf16* __restrict__ wgt3)       // [64*3][256][256]
{
    __shared__ bf16 smem[14336];   // As[2][4096] | Bs[2][3072]; epi: Cs[128][104]
    bf16* As = smem;
    bf16* Bs = smem + 8192;
    const int tid  = threadIdx.x;
    const int wave = tid >> 6, lane = tid & 63;
    const int row0 = blockIdx.y * 128;
    const int col0 = blockIdx.x * 96;

    const bf16* gA[4]; bf16* lA[4];
    #pragma unroll
    for (int j = 0; j < 4; ++j) {
        int s = tid + j * 256;               // 0..1023
        int reg = s >> 9, rem = s & 511, row = rem >> 2, quad = rem & 3;
        gA[j] = A + (size_t)(row0 + row) * Hh + reg * 32 + quad * 8;
        lA[j] = As + s * 8;
    }
    const bf16* gB[3]; bf16* lB[3];
    #pragma unroll
    for (int j = 0; j < 3; ++j) {
        int s = tid + j * 256;               // 0..767
        int reg = s / 384, rem = s - reg * 384, row = rem >> 2, quad = rem & 3;
        gB[j] = Bw + (size_t)(col0 + row) * Hh + reg * 32 + quad * 8;
        lB[j] = Bs + s * 8;
    }

    const int wm = wave & 1, wn = wave >> 1;
    const int fm = lane & 15, koct = (lane >> 4) * 8;

    floatx4 zero = {0.f, 0.f, 0.f, 0.f};
    floatx4 acc[4][3];
    #pragma unroll
    for (int i = 0; i < 4; ++i)
        #pragma unroll
        for (int j = 0; j < 3; ++j) acc[i][j] = zero;

    for (int k0 = 0; k0 < Hh; k0 += 64) {
        #pragma unroll
        for (int j = 0; j < 4; ++j) gl_lds16(gA[j] + k0, lA[j]);
        #pragma unroll
        for (int j = 0; j < 3; ++j) gl_lds16(gB[j] + k0, lB[j]);
        __syncthreads();
        #pragma unroll
        for (int q = 0; q < 2; ++q) {
            bf16x8 af[4], bfr[3];
            #pragma unroll
            for (int mt = 0; mt < 4; ++mt)
                af[mt] = *(const bf16x8*)&As[q * 4096 + (wm * 64 + mt * 16 + fm) * 32 + koct];
            #pragma unroll
            for (int nt = 0; nt < 3; ++nt)
                bfr[nt] = *(const bf16x8*)&Bs[q * 3072 + (wn * 48 + nt * 16 + fm) * 32 + koct];
            #pragma unroll
            for (int mt = 0; mt < 4; ++mt)
                #pragma unroll
                for (int nt = 0; nt < 3; ++nt)
                    acc[mt][nt] = __builtin_amdgcn_mfma_f32_16x16x32_bf16(
                        af[mt], bfr[nt], acc[mt][nt], 0, 0, 0);
        }
        __syncthreads();
    }

    // Epilogue: acc -> Cs[128][96] (pitch 104), then coalesced unscramble.
    const int b  = row0 >> 8;
    const int nb = row0 & 255;
    bf16* Cs = smem;
    #pragma unroll
    for (int nt = 0; nt < 3; ++nt) {
        int c = wn * 48 + nt * 16 + fm;
        float bl = bias[col0 + c];
        #pragma unroll
        for (int mt = 0; mt < 4; ++mt) {
            int rb = wm * 64 + mt * 16 + (lane >> 4) * 4;
            #pragma unroll
            for (int r = 0; r < 4; ++r)
                Cs[(rb + r) * 104 + c] = (bf16)(acc[mt][nt][r] + bl);
        }
    }
    __syncthreads();
    const int i0 = blockIdx.x * 32;
    #pragma unroll
    for (int j = 0; j < 6; ++j) {
        int s = tid + j * 256;               // 0..1535
        int t = s / 512, rem = s & 511, n = rem >> 2, q8 = rem & 3;
        bf16x8 v;
        #pragma unroll
        for (int u = 0; u < 8; ++u)
            v[u] = Cs[n * 104 + (q8 * 8 + u) * 3 + t];
        *(bf16x8*)&wgt3[((size_t)(b * 3 + t) << 16) + ((size_t)(nb + n) << 8) + i0 + q8 * 8] = v;
    }
}

// ---------------------------------------------------------------------------
// Stage 2: out[b][o][h] = sum_{t,i} wgt3[b][t][o][i] * kTp[b][h+t][i]
// Block = (b, 128-o, 256-h). 8 i-chunks of 32; staging via gl_lds16
// (halo rows 256..257 via plain load + ds write, divergence-safe).
// ---------------------------------------------------------------------------
__global__ __launch_bounds__(256, 2) void conv_mfma(
    const bf16* __restrict__ kTp,   // [64][1026][256]
    const bf16* __restrict__ wgt3,  // [64*3][256][256]
    float* __restrict__ out)        // [64][256][1024] fp32
{
    __shared__ bf16 As[12288];      // [t][o(128)][i(32)]  24 KB
    __shared__ bf16 Ks[8704];       // [row(258)][i(32)]  17 KB
    const int tid  = threadIdx.x;
    const int wave = tid >> 6, lane = tid & 63;
    const int b  = blockIdx.z;
    const int o0 = blockIdx.y * 128;
    const int h0 = blockIdx.x * 256;
    const int wm = wave & 1, wn = wave >> 1;
    const int fm = lane & 15, koct = (lane >> 4) * 8;

    const bf16* gA[6]; bf16* lA[6];
    #pragma unroll
    for (int j = 0; j < 6; ++j) {
        int s = tid + j * 256;               // 0..1535
        int t = s / 512, rem = s & 511, o = rem >> 2, iq = rem & 3;
        gA[j] = wgt3 + ((size_t)(b * 3 + t) << 16) + ((size_t)(o0 + o) << 8) + iq * 8;
        lA[j] = As + s * 8;
    }
    const bf16* kb = kTp + (size_t)b * KT_BSTRIDE;
    const bf16* gK[4]; bf16* lK[4];
    #pragma unroll
    for (int j = 0; j < 4; ++j) {
        int s = tid + j * 256;               // 0..1023 -> rows 0..255
        int r = s >> 2, quad = s & 3;
        gK[j] = kb + (size_t)(h0 + r) * 256 + quad * 8;
        lK[j] = Ks + s * 8;
    }

    floatx4 zero = {0.f, 0.f, 0.f, 0.f};
    floatx4 acc[4][8];
    #pragma unroll
    for (int i = 0; i < 4; ++i)
        #pragma unroll
        for (int j = 0; j < 8; ++j) acc[i][j] = zero;

    for (int ic = 0; ic < 8; ++ic) {
        const int i0 = ic * 32;
        __syncthreads();
        #pragma unroll
        for (int j = 0; j < 6; ++j) gl_lds16(gA[j] + i0, lA[j]);
        #pragma unroll
        for (int j = 0; j < 4; ++j) gl_lds16(gK[j] + i0, lK[j]);
        if (tid < 8) {                       // halo rows 256..257
            int r = 256 + (tid >> 2), q = tid & 3;
            bf16x8 v = *(const bf16x8*)&kb[(size_t)(h0 + r) * 256 + i0 + q * 8];
            *(bf16x8*)&Ks[r * 32 + q * 8] = v;
        }
        __syncthreads();
        #pragma unroll
        for (int t = 0; t < 3; ++t) {
            bf16x8 af[4], bfr[8];
            #pragma unroll
            for (int mt = 0; mt < 4; ++mt)
                af[mt] = *(const bf16x8*)&As[t * 4096 + (wm * 64 + mt * 16 + fm) * 32 + koct];
            #pragma unroll
            for (int nt = 0; nt < 8; ++nt)
                bfr[nt] = *(const bf16x8*)&Ks[(wn * 128 + nt * 16 + fm + t) * 32 + koct];
            #pragma unroll
            for (int mt = 0; mt < 4; ++mt)
                #pragma unroll
                for (int nt = 0; nt < 8; ++nt)
                    acc[mt][nt] = __builtin_amdgcn_mfma_f32_16x16x32_bf16(
                        af[mt], bfr[nt], acc[mt][nt], 0, 0, 0);
        }
    }

    #pragma unroll
    for (int mt = 0; mt < 4; ++mt) {
        int o = o0 + wm * 64 + mt * 16 + (lane >> 4) * 4;
        #pragma unroll
        for (int nt = 0; nt < 8; ++nt) {
            int h = h0 + wn * 128 + nt * 16 + fm;
            #pragma unroll
            for (int r = 0; r < 4; ++r)
                out[((size_t)(b * 256 + o + r) << 10) + h] = acc[mt][nt][r];
        }
    }
}

// ---------------------------------------------------------------------------
// Stage 3: LayerNorm over H per (b,o) row, in place on d_out (fp32).
// ---------------------------------------------------------------------------
__global__ __launch_bounds__(256) void ln_kernel(
    float* __restrict__ io, const float* __restrict__ gamma,
    const float* __restrict__ beta)
{
    const int row = blockIdx.x;
    const int tid = threadIdx.x;
    float* p = io + ((size_t)row << 10);
    float4 v = ((const float4*)p)[tid];
    float x[4] = {v.x, v.y, v.z, v.w};
    float s1 = x[0] + x[1] + x[2] + x[3];
    float s2 = x[0]*x[0] + x[1]*x[1] + x[2]*x[2] + x[3]*x[3];
    #pragma unroll
    for (int m = 1; m < 64; m <<= 1) {
        s1 += __shfl_xor(s1, m, 64);
        s2 += __shfl_xor(s2, m, 64);
    }
    __shared__ float r1[4], r2[4];
    if ((tid & 63) == 0) { r1[tid >> 6] = s1; r2[tid >> 6] = s2; }
    __syncthreads();
    float S1 = r1[0] + r1[1] + r1[2] + r1[3];
    float S2 = r2[0] + r2[1] + r2[2] + r2[3];
    float mu   = S1 * (1.0f / 1024.0f);
    float var  = S2 * (1.0f / 1024.0f) - mu * mu;
    float rstd = rsqrtf(var + 1e-5f);
    float4 g  = ((const float4*)gamma)[tid];
    float4 be = ((const float4*)beta)[tid];
    float4 o;
    o.x = (x[0] - mu) * rstd * g.x + be.x;
    o.y = (x[1] - mu) * rstd * g.y + be.y;
    o.z = (x[2] - mu) * rstd * g.z + be.z;
    o.w = (x[3] - mu) * rstd * g.w + be.w;
    ((float4*)p)[tid] = o;
}

extern "C" void kernel_launch(void* const* d_in, const int* in_sizes, int n_in,
                              void* d_out, int out_size, void* d_ws, size_t ws_size,
                              hipStream_t stream) {
    const float* f     = (const float*)d_in[0];
    const float* kin   = (const float*)d_in[1];
    const float* W_lin = (const float*)d_in[2];
    const float* b_lin = (const float*)d_in[3];
    const float* gamma = (const float*)d_in[4];
    const float* beta  = (const float*)d_in[5];
    float* out = (float*)d_out;

    char* ws = (char*)d_ws;
    bf16* fbf  = (bf16*)(ws);                   // 33.55 MB; dead after gemm1
    bf16* kTp  = (bf16*)(ws);                   // 33.62 MB, aliases fbf (written after gemm1)
    bf16* wlbf = (bf16*)(ws + 33619968);        // 1.57 MB
    bf16* wgt3 = (bf16*)(ws + 35192832);        // 25.17 MB -> total ~60.4 MB

    cast2_kernel<<<17152, 256, 0, stream>>>(f, W_lin, fbf, wlbf);
    gemm1_mfma<<<dim3(8, 128), 256, 0, stream>>>(fbf, wlbf, b_lin, wgt3);
    kT_kernel<<<dim3(16, 4, 64), 256, 0, stream>>>(kin, kTp);
    conv_mfma<<<dim3(4, 2, 64), 256, 0, stream>>>(kTp, wgt3, out);
    ln_kernel<<<16384, 256, 0, stream>>>(out, gamma, beta);
}